// Round 4
// baseline (157.891 us; speedup 1.0000x reference)
//
#include <hip/hip_runtime.h>

namespace {

typedef float v2f __attribute__((ext_vector_type(2)));

constexpr int NTAGS = 64;
constexpr int START_T = 62;
constexpr int STOP_T = 63;
constexpr int Bc = 512;
constexpr int Lc = 512;

template <int CTRL>
__device__ __forceinline__ float dpp_add(float x) {
  // x + quad_perm(x): pure-VALU cross-lane add within groups of 4 lanes.
  return x + __int_as_float(__builtin_amdgcn_update_dpp(
                 0, __float_as_int(x), CTRL, 0xf, 0xf, true));
}

__device__ __forceinline__ float wave_max(float v) {
#pragma unroll
  for (int off = 32; off >= 1; off >>= 1)
    v = fmaxf(v, __shfl_xor(v, off, 64));
  return v;
}

__device__ __forceinline__ float wave_sum(float v) {
#pragma unroll
  for (int off = 32; off >= 1; off >>= 1)
    v += __shfl_xor(v, off, 64);
  return v;
}

// One wave per batch. lane -> (lr = lane>>2, c = lane&3).
// Lane owns rows {lr+16k, k=0..3} and j-chunk c (16 j's with (j&15)>>2 == c).
// v stored in LDS in sigma-order: sigma(j) = (j&15)*4 + (j>>4), so each
// chunk is 4 contiguous float4 and each lane's 4 outputs are one float4
// at word 4*lr. Exp-domain state: v = exp(alpha - Msum*ln2); per-step
// power-of-2 rescale from the (stale) exponent of v_0 -- off critical path.
__global__ __launch_bounds__(64, 1) void crf_scan(
    const float* __restrict__ inputs,   // [B, L, 64]
    const int* __restrict__ tags,       // [B, L]
    const int* __restrict__ mask,       // [B, L]
    const float* __restrict__ trans,    // [64, 64]
    float* __restrict__ partial) {      // [B]
  __shared__ float4 vb4[16];
  float* vb1 = reinterpret_cast<float*>(vb4);

  const int b = blockIdx.x;
  const int lane = threadIdx.x;
  const int lr = lane >> 2;
  const int c = lane & 3;

  // E[k][t] = exp(trans[lr+16k][j(t,c)]), j(t,c) = 16*(t&3) + 4c + (t>>2).
  // Stored as 8 v2f per row, pair p = (t=2p, t=2p+1).
#define DECLE(k) v2f E##k##_0, E##k##_1, E##k##_2, E##k##_3, \
                     E##k##_4, E##k##_5, E##k##_6, E##k##_7;
  DECLE(0) DECLE(1) DECLE(2) DECLE(3)
#define LOADE(k)                                                       \
  {                                                                    \
    const float* tp = trans + (lr + 16 * k) * NTAGS + 4 * c;           \
    E##k##_0 = (v2f){__expf(tp[0]),  __expf(tp[16])};                  \
    E##k##_1 = (v2f){__expf(tp[32]), __expf(tp[48])};                  \
    E##k##_2 = (v2f){__expf(tp[1]),  __expf(tp[17])};                  \
    E##k##_3 = (v2f){__expf(tp[33]), __expf(tp[49])};                  \
    E##k##_4 = (v2f){__expf(tp[2]),  __expf(tp[18])};                  \
    E##k##_5 = (v2f){__expf(tp[34]), __expf(tp[50])};                  \
    E##k##_6 = (v2f){__expf(tp[3]),  __expf(tp[19])};                  \
    E##k##_7 = (v2f){__expf(tp[35]), __expf(tp[51])};                  \
  }
  LOADE(0) LOADE(1) LOADE(2) LOADE(3)

  const float* emit_base = inputs + (size_t)b * Lc * NTAGS;
  const int* mask_b = mask + b * Lc;
  const int* tags_b = tags + b * Lc;

  int Msum = 0;
  // init: v one-hot at tag START_T=62 -> sigma(62) = 14*4+3 = 59
  vb1[lane] = (lane == 59) ? 1.0f : 0.0f;
  __builtin_amdgcn_wave_barrier();

#define ROWF(k)                                                        \
    v2f a##k##0 = E##k##_0 * (v2f){u0.x, u0.y};                        \
    v2f a##k##1 = E##k##_1 * (v2f){u0.z, u0.w};                        \
    a##k##0 += E##k##_2 * (v2f){u1.x, u1.y};                           \
    a##k##1 += E##k##_3 * (v2f){u1.z, u1.w};                           \
    a##k##0 += E##k##_4 * (v2f){u2.x, u2.y};                           \
    a##k##1 += E##k##_5 * (v2f){u2.z, u2.w};                           \
    a##k##0 += E##k##_6 * (v2f){u3.x, u3.y};                           \
    a##k##1 += E##k##_7 * (v2f){u3.z, u3.w};

#define STEP(W0, W1, W2, W3, MIDX)                                     \
  {                                                                    \
    float4 u0 = vb4[4 * c + 0], u1 = vb4[4 * c + 1];                   \
    float4 u2 = vb4[4 * c + 2], u3 = vb4[4 * c + 3];                   \
    /* rescale factor from stale exponent of v_0 (lane 0's u0.x) */    \
    const int sb = __builtin_amdgcn_readlane(__float_as_int(u0.x), 0); \
    const unsigned e0 = ((unsigned)sb >> 23) & 0xffu;                  \
    const int d = (e0 == 0u) ? 0 : (int)e0 - 127;                      \
    Msum += d;                                                         \
    const float rs = __uint_as_float((unsigned)(127 - d) << 23);       \
    const int mv = __builtin_amdgcn_readlane(mrow, (MIDX));            \
    float s0, s1, s2, s3;                                              \
    if (mv) {                                                          \
      ROWF(0) ROWF(1) ROWF(2) ROWF(3)                                  \
      v2f t0 = a00 + a01, t1 = a10 + a11;                              \
      v2f t2 = a20 + a21, t3 = a30 + a31;                              \
      s0 = t0.x + t0.y; s1 = t1.x + t1.y;                              \
      s2 = t2.x + t2.y; s3 = t3.x + t3.y;                              \
      s0 = dpp_add<0xB1>(s0); s1 = dpp_add<0xB1>(s1);                  \
      s2 = dpp_add<0xB1>(s2); s3 = dpp_add<0xB1>(s3);                  \
      s0 = dpp_add<0x4E>(s0); s1 = dpp_add<0x4E>(s1);                  \
      s2 = dpp_add<0x4E>(s2); s3 = dpp_add<0x4E>(s3);                  \
      s0 *= (W0) * rs; s1 *= (W1) * rs;                                \
      s2 *= (W2) * rs; s3 *= (W3) * rs;                                \
    } else {                                                           \
      v2f q0 = ((v2f){u0.x, u0.y} + (v2f){u0.z, u0.w}) +               \
               ((v2f){u1.x, u1.y} + (v2f){u1.z, u1.w});                \
      v2f q1 = ((v2f){u2.x, u2.y} + (v2f){u2.z, u2.w}) +               \
               ((v2f){u3.x, u3.y} + (v2f){u3.z, u3.w});                \
      v2f q = q0 + q1;                                                 \
      float ss = q.x + q.y;                                            \
      ss = dpp_add<0xB1>(ss); ss = dpp_add<0x4E>(ss);                  \
      ss *= rs;                                                        \
      s0 = s1 = s2 = s3 = ss;                                          \
    }                                                                  \
    __builtin_amdgcn_wave_barrier();                                   \
    if ((lane & 3) == 0) vb4[lr] = make_float4(s0, s1, s2, s3);        \
    __builtin_amdgcn_wave_barrier();                                   \
  }

  // w = exp(emit) prefetch: bank[q step][k row], 4 steps x 4 rows.
  float wA[4][4], wB[4][4];
#define PRE(Wb, ST)                                                    \
  {                                                                    \
    int s_ = (ST); s_ = s_ > (Lc - 4) ? (Lc - 4) : s_;                 \
    _Pragma("unroll") for (int q = 0; q < 4; ++q) {                    \
      const float* pp = emit_base + (size_t)(s_ + q) * NTAGS + lr;     \
      Wb[q][0] = __expf(pp[0]);                                        \
      Wb[q][1] = __expf(pp[16]);                                       \
      Wb[q][2] = __expf(pp[32]);                                       \
      Wb[q][3] = __expf(pp[48]);                                       \
    }                                                                  \
  }

  PRE(wA, 0)
  int mrow = mask_b[lane];

  for (int chunk = 0; chunk < 8; ++chunk) {
    const int cbase = chunk * 64;
    int mrow_nxt = mask_b[(chunk < 7 ? cbase + 64 : cbase) + lane];
    for (int gp = 0; gp < 8; ++gp) {
      const int base = cbase + gp * 8;
      const int mb = gp * 8;
      PRE(wB, base + 4)
      STEP(wA[0][0], wA[0][1], wA[0][2], wA[0][3], mb + 0)
      STEP(wA[1][0], wA[1][1], wA[1][2], wA[1][3], mb + 1)
      STEP(wA[2][0], wA[2][1], wA[2][2], wA[2][3], mb + 2)
      STEP(wA[3][0], wA[3][1], wA[3][2], wA[3][3], mb + 3)
      PRE(wA, base + 8)
      STEP(wB[0][0], wB[0][1], wB[0][2], wB[0][3], mb + 4)
      STEP(wB[1][0], wB[1][1], wB[1][2], wB[1][3], mb + 5)
      STEP(wB[2][0], wB[2][1], wB[2][2], wB[2][3], mb + 6)
      STEP(wB[3][0], wB[3][1], wB[3][2], wB[3][3], mb + 7)
    }
    mrow = mrow_nxt;
  }

  // ---- epilogue ----
  // C = Msum * ln2 with exact hi/lo split (hi = 355/512, 9 mantissa bits).
  const float mf = (float)Msum;
  const float C = fmaf(mf, -2.1219444e-4f, mf * 0.693359375f);

  const int sig = ((lane & 15) << 2) | (lane >> 4);  // sigma(lane)
  float alphav = __logf(vb1[sig]) + C;
  float term = alphav + trans[STOP_T * NTAGS + lane];
  float mx = wave_max(term);
  float sden = wave_sum(__expf(term - mx));
  float logden = mx + __logf(sden);

  // numerator score: lanes parallel over timesteps (exact)
  float sc = 0.0f;
  for (int l = lane; l < Lc; l += 64) {
    int tl = tags_b[l];
    float mfl = (float)mask_b[l];
    if (l < Lc - 1) {
      int tn = tags_b[l + 1];
      float mfn = (float)mask_b[l + 1];
      sc += trans[tn * NTAGS + tl] * mfn +
            emit_base[(size_t)l * NTAGS + tl] * mfl;
    } else {
      sc += trans[STOP_T * NTAGS + tl] +
            emit_base[(size_t)l * NTAGS + tl] * mfl;
    }
  }
  if (lane == 0) sc += trans[tags_b[0] * NTAGS + START_T];
  float score = wave_sum(sc);

  if (lane == 0) partial[b] = score - logden;
}

__global__ void crf_reduce(const float* __restrict__ partial,
                           float* __restrict__ out) {
  const int lane = threadIdx.x;
  float s = 0.0f;
  for (int i = lane; i < Bc; i += 64) s += partial[i];
  s = wave_sum(s);
  if (lane == 0) out[0] = s;
}

}  // namespace

extern "C" void kernel_launch(void* const* d_in, const int* in_sizes, int n_in,
                              void* d_out, int out_size, void* d_ws,
                              size_t ws_size, hipStream_t stream) {
  const float* inputs = (const float*)d_in[0];
  const int* tags = (const int*)d_in[1];
  const int* mask = (const int*)d_in[2];
  const float* trans = (const float*)d_in[3];
  float* out = (float*)d_out;
  float* partial = (float*)d_ws;  // B floats of scratch

  crf_scan<<<Bc, 64, 0, stream>>>(inputs, tags, mask, trans, partial);
  crf_reduce<<<1, 64, 0, stream>>>(partial, out);
}